// Round 6
// baseline (264.397 us; speedup 1.0000x reference)
//
#include <hip/hip_runtime.h>

#define B_  32
#define C_  256
#define H_  56
#define W_  56
#define HW  3136      // H_*W_
#define KK  9
#define NP  8             // planes per block (8 | 256 -> batch-uniform)
#define NPLANES (B_*C_)   // 8192
#define GRID (NPLANES/NP) // 1024 = 256 CUs * 4 blocks -> co-resident by resource math

typedef float v4f __attribute__((ext_vector_type(4)));

// Write the staged registers into the 58x58 zero-padded interior (R0-verified map).
__device__ __forceinline__ void stage_write(float* __restrict__ dst, int t,
                                            float4 v0, float4 v1, float4 v2, float4 v3) {
    int s, r, c0, base;
    s = t;        r = s / 14; c0 = (s % 14) * 4; base = (r + 1) * 58 + c0 + 1;
    dst[base] = v0.x; dst[base + 1] = v0.y; dst[base + 2] = v0.z; dst[base + 3] = v0.w;
    s = t + 256;  r = s / 14; c0 = (s % 14) * 4; base = (r + 1) * 58 + c0 + 1;
    dst[base] = v1.x; dst[base + 1] = v1.y; dst[base + 2] = v1.z; dst[base + 3] = v1.w;
    s = t + 512;  r = s / 14; c0 = (s % 14) * 4; base = (r + 1) * 58 + c0 + 1;
    dst[base] = v2.x; dst[base + 1] = v2.y; dst[base + 2] = v2.z; dst[base + 3] = v2.w;
    if (t < 16) {
        s = t + 768; r = s / 14; c0 = (s % 14) * 4; base = (r + 1) * 58 + c0 + 1;
        dst[base] = v3.x; dst[base + 1] = v3.y; dst[base + 2] = v3.z; dst[base + 3] = v3.w;
    }
}

// Device-scope grid barrier: cnt/go live in workspace, zeroed per launch by
// hipMemsetAsync. All cross-block ordering via AGENT-scope atomics (per-XCD
// L2s are not coherent for plain accesses).
__device__ __forceinline__ void grid_barrier(int* cnt, int* go, int t) {
    __syncthreads();
    if (t == 0) {
        if (__hip_atomic_fetch_add(cnt, 1, __ATOMIC_ACQ_REL,
                                   __HIP_MEMORY_SCOPE_AGENT) == GRID - 1) {
            __hip_atomic_store(go, 1, __ATOMIC_RELEASE, __HIP_MEMORY_SCOPE_AGENT);
        } else {
            while (__hip_atomic_load(go, __ATOMIC_ACQUIRE,
                                     __HIP_MEMORY_SCOPE_AGENT) == 0)
                __builtin_amdgcn_s_sleep(2);
        }
    }
    __syncthreads();
}

// ---------------------------------------------------------------------------
// Fused kernel. x is read from HBM exactly ONCE (phase 1) and carried across
// the grid barrier in registers; phase 2 never reads x globally, so its HBM
// traffic is a pure full-line NT write stream.
// pooled (pp) uses a 64B-per-block padded layout pp[plane>>3][16] so no cache
// line is written by two blocks; all pp accesses are AGENT-scope atomics.
// ---------------------------------------------------------------------------
__global__ __launch_bounds__(256, 4)
void fused_kernel(const float* __restrict__ x,
                  const float* __restrict__ Wk,
                  const float* __restrict__ bk,
                  float* __restrict__ pp,      // padded pooled [1024][16]
                  int* cnt, int* go,
                  float* __restrict__ out) {
    __shared__ float  tile[58 * 58];
    __shared__ float  ost[56 * 56];
    __shared__ float4 remL[NP][16];
    __shared__ float  wred[NP][4];
    __shared__ float  wsh[12];
    __shared__ float  psh[C_];                  // this batch's pooled row

    const int t    = threadIdx.x;
    const int lane = t & 63;
    const int wv   = t >> 6;
    const int p0   = blockIdx.x * NP;           // planes p0..p0+7, same batch
    const int b    = p0 >> 8;                   // batch (uniform over block)

    // ---------------- Phase 1: load 8 planes to registers + means ----------
    float4 s[NP][3];
    float  psum[NP];
    #pragma unroll
    for (int p = 0; p < NP; ++p) {
        const float4* xp = (const float4*)(x + (size_t)(p0 + p) * HW);
        float4 a = xp[t], b4 = xp[t + 256], c4 = xp[t + 512];
        s[p][0] = a; s[p][1] = b4; s[p][2] = c4;
        float acc = (a.x + a.y) + (a.z + a.w)
                  + (b4.x + b4.y) + (b4.z + b4.w)
                  + (c4.x + c4.y) + (c4.z + c4.w);
        if (t < 16) {
            float4 r = xp[t + 768];
            remL[p][t] = r;                      // tail lives in LDS across sync
            acc += (r.x + r.y) + (r.z + r.w);
        }
        psum[p] = acc;
    }
    #pragma unroll
    for (int p = 0; p < NP; ++p) {
        float sm = psum[p];
        #pragma unroll
        for (int off = 32; off > 0; off >>= 1)
            sm += __shfl_down(sm, off, 64);
        if (lane == 0) wred[p][wv] = sm;
    }
    __syncthreads();
    if (t < NP) {
        const int q = p0 + t;
        const float m = (wred[t][0] + wred[t][1]) + (wred[t][2] + wred[t][3]);
        __hip_atomic_store(&pp[(size_t)(q >> 3) * 16 + (q & 7)],
                           m * (1.0f / (float)HW),
                           __ATOMIC_RELAXED, __HIP_MEMORY_SCOPE_AGENT);
    }

    grid_barrier(cnt, go, t);                    // all pooled values visible

    // ---------------- Phase 2 preamble: pooled row -> LDS, halo zero -------
    {
        const int row = (b << 5) + (t >> 3);     // padded pp row for channel t
        psh[t] = __hip_atomic_load(&pp[(size_t)row * 16 + (t & 7)],
                                   __ATOMIC_RELAXED, __HIP_MEMORY_SCOPE_AGENT);
    }
    if (t < 58) { tile[t] = 0.f; tile[57 * 58 + t] = 0.f; }
    if (t < 56) { tile[(t + 1) * 58] = 0.f; tile[(t + 1) * 58 + 57] = 0.f; }
    __syncthreads();                             // psh + halo ready

    // ---------------- Phase 2: per plane kerngen + stencil + NT out --------
    #pragma unroll
    for (int p = 0; p < NP; ++p) {
        // Stage plane p from registers (LDS-only; no global reads).
        stage_write(tile, t, s[p][0], s[p][1], s[p][2], remL[p][t & 15]);

        // Inline kerngen (R0-verified): tap o = t/16, 16 lanes x 16 channels.
        if (t < 144) {
            const int c  = (p0 + p) & 255;
            const int o  = t >> 4;               // 0..8
            const int ch = (t & 15) << 4;        // 0,16,...,240
            const int og = c * KK + o;
            const float4* wr  = (const float4*)(Wk + (size_t)og * C_ + ch);
            const float4* pr4 = (const float4*)(psh + ch);
            float4 w0v = wr[0], w1v = wr[1], w2v = wr[2], w3v = wr[3];
            float4 P0 = pr4[0], P1 = pr4[1], P2 = pr4[2], P3 = pr4[3];
            float sv = w0v.x * P0.x + w0v.y * P0.y + w0v.z * P0.z + w0v.w * P0.w
                     + w1v.x * P1.x + w1v.y * P1.y + w1v.z * P1.z + w1v.w * P1.w
                     + w2v.x * P2.x + w2v.y * P2.y + w2v.z * P2.z + w2v.w * P2.w
                     + w3v.x * P3.x + w3v.y * P3.y + w3v.z * P3.z + w3v.w * P3.w;
            #pragma unroll
            for (int off = 8; off > 0; off >>= 1)
                sv += __shfl_down(sv, off, 16);
            if ((t & 15) == 0)
                wsh[o] = fmaxf(sv + bk[og], 0.f);
        }
        __syncthreads();                         // B1: tile + wsh ready

        const float w0 = __int_as_float(__builtin_amdgcn_readfirstlane(__float_as_int(wsh[0])));
        const float w1 = __int_as_float(__builtin_amdgcn_readfirstlane(__float_as_int(wsh[1])));
        const float w2 = __int_as_float(__builtin_amdgcn_readfirstlane(__float_as_int(wsh[2])));
        const float w3 = __int_as_float(__builtin_amdgcn_readfirstlane(__float_as_int(wsh[3])));
        const float w4 = __int_as_float(__builtin_amdgcn_readfirstlane(__float_as_int(wsh[4])));
        const float w5 = __int_as_float(__builtin_amdgcn_readfirstlane(__float_as_int(wsh[5])));
        const float w6 = __int_as_float(__builtin_amdgcn_readfirstlane(__float_as_int(wsh[6])));
        const float w7 = __int_as_float(__builtin_amdgcn_readfirstlane(__float_as_int(wsh[7])));
        const float w8 = __int_as_float(__builtin_amdgcn_readfirstlane(__float_as_int(wsh[8])));

        // Stencil (R0-verified 2x4 tiles) -> LDS out-stage.
        for (int i = t; i < 392; i += 256) {
            const int rp = i / 14;
            const int c0 = (i % 14) * 4;
            const float* R0 = &tile[(2 * rp + 0) * 58 + c0];
            const float* R1 = &tile[(2 * rp + 1) * 58 + c0];
            const float* R2 = &tile[(2 * rp + 2) * 58 + c0];
            const float* R3 = &tile[(2 * rp + 3) * 58 + c0];
            float2 p0v = *(const float2*)(R0), p1v = *(const float2*)(R0 + 2), p2v = *(const float2*)(R0 + 4);
            float2 q0v = *(const float2*)(R1), q1v = *(const float2*)(R1 + 2), q2v = *(const float2*)(R1 + 4);
            float2 r0v = *(const float2*)(R2), r1v = *(const float2*)(R2 + 2), r2v = *(const float2*)(R2 + 4);
            float2 u0v = *(const float2*)(R3), u1v = *(const float2*)(R3 + 2), u2v = *(const float2*)(R3 + 4);
            const float a0 = p0v.x, a1 = p0v.y, a2 = p1v.x, a3 = p1v.y, a4 = p2v.x, a5 = p2v.y;
            const float b0 = q0v.x, b1 = q0v.y, b2 = q1v.x, b3 = q1v.y, b4 = q2v.x, b5 = q2v.y;
            const float e0 = r0v.x, e1 = r0v.y, e2 = r1v.x, e3 = r1v.y, e4 = r2v.x, e5 = r2v.y;
            const float d0 = u0v.x, d1 = u0v.y, d2 = u1v.x, d3 = u1v.y, d4 = u2v.x, d5 = u2v.y;

            v4f t0, t1;
            t0.x = a0*w0 + a1*w1 + a2*w2 + b0*w3 + b1*w4 + b2*w5 + e0*w6 + e1*w7 + e2*w8;
            t0.y = a1*w0 + a2*w1 + a3*w2 + b1*w3 + b2*w4 + b3*w5 + e1*w6 + e2*w7 + e3*w8;
            t0.z = a2*w0 + a3*w1 + a4*w2 + b2*w3 + b3*w4 + b4*w5 + e2*w6 + e3*w7 + e4*w8;
            t0.w = a3*w0 + a4*w1 + a5*w2 + b3*w3 + b4*w4 + b5*w5 + e3*w6 + e4*w7 + e5*w8;
            t1.x = b0*w0 + b1*w1 + b2*w2 + e0*w3 + e1*w4 + e2*w5 + d0*w6 + d1*w7 + d2*w8;
            t1.y = b1*w0 + b2*w1 + b3*w2 + e1*w3 + e2*w4 + e3*w5 + d1*w6 + d2*w7 + d3*w8;
            t1.z = b2*w0 + b3*w1 + b4*w2 + e2*w3 + e3*w4 + e4*w5 + d2*w6 + d3*w7 + d4*w8;
            t1.w = b3*w0 + b4*w1 + b5*w2 + e3*w3 + e4*w4 + e5*w5 + d3*w6 + d4*w7 + d5*w8;

            *(v4f*)&ost[(2 * rp + 0) * 56 + c0] = t0;
            *(v4f*)&ost[(2 * rp + 1) * 56 + c0] = t1;
        }
        __syncthreads();                         // B2: ost complete, tile free

        // Copy-out: contiguous full-line NT stores (pure HBM write stream).
        {
            float* op = out + (size_t)(p0 + p) * HW;
            const v4f* os = (const v4f*)ost;
            __builtin_nontemporal_store(os[t],       (v4f*)op + t);
            __builtin_nontemporal_store(os[t + 256], (v4f*)op + t + 256);
            __builtin_nontemporal_store(os[t + 512], (v4f*)op + t + 512);
            if (t < 16)
                __builtin_nontemporal_store(os[t + 768], (v4f*)op + t + 768);
        }
        // Next iteration's stage_write (tile) + kerngen (wsh) start after B2;
        // ost is rewritten only after the next B1 -> copy-out reads are safe.
    }
}

extern "C" void kernel_launch(void* const* d_in, const int* in_sizes, int n_in,
                              void* d_out, int out_size, void* d_ws, size_t ws_size,
                              hipStream_t stream) {
    const float* x  = (const float*)d_in[0];   // [B,C,H,W]
    const float* Wk = (const float*)d_in[1];   // [C*K*K, C]
    const float* bk = (const float*)d_in[2];   // [C*K*K]
    float* out = (float*)d_out;                // [B,C,H,W]

    float* pp = (float*)d_ws;                  // padded pooled [1024][16] = 64 KB
    int* cnt  = (int*)((char*)d_ws + 65536);         // own cache line
    int* go   = (int*)((char*)d_ws + 65536 + 128);   // separate cache line

    // Zero the barrier state each launch (capture-legal; harness uses
    // hipMemsetAsync itself).
    hipMemsetAsync((char*)d_ws + 65536, 0, 256, stream);

    fused_kernel<<<dim3(GRID), dim3(256), 0, stream>>>(x, Wk, bk, pp, cnt, go, out);
}

// Round 7
// 204.263 us; speedup vs baseline: 1.2944x; 1.2944x over previous
//
#include <hip/hip_runtime.h>

#define B_  32
#define C_  256
#define H_  56
#define W_  56
#define HW  3136      // H_*W_
#define KK  9
#define NPLANES (B_*C_)   // 8192

typedef float v4f __attribute__((ext_vector_type(4)));

// ---------------------------------------------------------------------------
// Kernel 1: global average pool. One WAVE per (b,c) plane, 4 planes/block.
// Pure shuffle reduction; at the HBM read floor (~17 us) — unchanged.
// ---------------------------------------------------------------------------
__global__ __launch_bounds__(256) void pool_kernel(const float* __restrict__ x,
                                                   float* __restrict__ pooled) {
    const int wid  = threadIdx.x >> 6;
    const int lane = threadIdx.x & 63;
    const int plane = blockIdx.x * 4 + wid;             // 2048 blocks * 4 waves
    const float4* xp = (const float4*)(x + (size_t)plane * HW);

    float s = 0.f;
    #pragma unroll
    for (int k = 0; k < 12; ++k) {                      // 12*64 = 768 strips
        float4 v = xp[lane + k * 64];
        s += (v.x + v.y) + (v.z + v.w);
    }
    if (lane < 16) {                                    // remainder 768..783
        float4 v = xp[768 + lane];
        s += (v.x + v.y) + (v.z + v.w);
    }
    #pragma unroll
    for (int off = 32; off > 0; off >>= 1)
        s += __shfl_down(s, off, 64);
    if (lane == 0)
        pooled[plane] = s * (1.0f / (float)HW);
}

// ---------------------------------------------------------------------------
// Kernel 2: 2 planes/block; 8x4 outputs per thread with rolling vertical
// accumulation. Vertical read redundancy 2.05x -> 1.25x (205 -> 128 MB of
// L2/L3 read traffic); horizontal halos via 16-lane shuffles; no LDS tile.
//   * kerngen re-shaped: 9 taps x 8 lanes x 32 channels, threads 0..143
//     cover BOTH planes; x-row loads issued before the barrier fly under it.
//   * thread map: slot s = wave*4 + (lane>>4) in [0,14): plane = s/7,
//     row-octet rq = s%7; col group k = lane&15 (k<14 active).
//   * ~96 live VGPRs, __launch_bounds__(256,4) -> no spill, 4 blocks/CU.
// ---------------------------------------------------------------------------
__global__ __launch_bounds__(256, 4) void dconv_kernel(const float* __restrict__ x,
                                                       const float* __restrict__ pooled,
                                                       const float* __restrict__ Wk,
                                                       const float* __restrict__ bk,
                                                       float* __restrict__ out) {
    const int p0 = blockIdx.x * 2;                      // planes p0, p0+1 (same batch)
    const int t  = threadIdx.x;
    __shared__ float wsh[2][12];

    // ---- stencil thread map (computed first so x loads issue ASAP) ----
    const int lane = t & 63;
    const int k    = lane & 15;                         // col group
    const int g    = lane >> 4;
    const int wv   = t >> 6;
    const int s    = wv * 4 + g;                        // 0..15
    const int sp   = (s < 14) ? s : 13;
    const int pl   = sp / 7;                            // plane select 0/1
    const int rq   = sp % 7;                            // row octet 0..6
    const int kc   = (k < 14) ? k : 13;
    const int c0   = kc << 2;                           // col base 0..52
    const bool act = (s < 14) && (k < 14);
    const int plane = p0 + pl;
    const float* xp = x + (size_t)plane * HW;

    // ---- issue all 10 input-row loads up front (fly under kerngen) ----
    float4 m[10];
    #pragma unroll
    for (int j = 0; j < 10; ++j) {
        int rr = rq * 8 - 1 + j;                        // rows rq*8-1 .. rq*8+8
        rr = rr < 0 ? 0 : (rr > 55 ? 55 : rr);          // clamped, in-bounds
        m[j] = *(const float4*)(xp + rr * W_ + c0);
    }
    if (rq == 0) { m[0].x = 0.f; m[0].y = 0.f; m[0].z = 0.f; m[0].w = 0.f; }  // row -1
    if (rq == 6) { m[9].x = 0.f; m[9].y = 0.f; m[9].z = 0.f; m[9].w = 0.f; }  // row 56

    // ---- kerngen: 2 planes, tap o: 8 lanes x 32 channels ----
    if (t < 144) {
        const int q  = t / 72;                          // plane select
        const int r  = t % 72;
        const int o  = r >> 3;                          // 0..8
        const int ch = (r & 7) << 5;                    // 0,32,...,224
        const int c  = (p0 + q) & 255;
        const int b  = p0 >> 8;
        const int og = c * KK + o;
        const float4* wr = (const float4*)(Wk + (size_t)og * C_ + ch);
        const float4* pr = (const float4*)(pooled + b * C_ + ch);
        float sv = 0.f;
        #pragma unroll
        for (int i = 0; i < 8; ++i) {
            float4 w = wr[i], p = pr[i];
            sv += w.x * p.x + w.y * p.y + w.z * p.z + w.w * p.w;
        }
        sv += __shfl_down(sv, 4, 8);
        sv += __shfl_down(sv, 2, 8);
        sv += __shfl_down(sv, 1, 8);
        if ((r & 7) == 0)
            wsh[q][o] = fmaxf(sv + bk[og], 0.f);
    }
    __syncthreads();

    // Taps (per-lane LDS reads; 2 distinct addresses per wave -> broadcast).
    const float w0 = wsh[pl][0], w1 = wsh[pl][1], w2 = wsh[pl][2],
                w3 = wsh[pl][3], w4 = wsh[pl][4], w5 = wsh[pl][5],
                w6 = wsh[pl][6], w7 = wsh[pl][7], w8 = wsh[pl][8];

    // ---- rolling accumulation: input row j feeds out rows j, j-1, j-2 ----
    float acc[8][4];
    #pragma unroll
    for (int o = 0; o < 8; ++o) {
        acc[o][0] = 0.f; acc[o][1] = 0.f; acc[o][2] = 0.f; acc[o][3] = 0.f;
    }
    #pragma unroll
    for (int j = 0; j < 10; ++j) {
        const float4 mm = m[j];
        float ml = __shfl_up(mm.w, 1, 16);              // col c0-1 from lane k-1
        float mr = __shfl_down(mm.x, 1, 16);            // col c0+4 from lane k+1
        if (k == 0)  ml = 0.f;                          // global left edge
        if (k >= 13) mr = 0.f;                          // global right edge
        const float n0 = ml, n1 = mm.x, n2 = mm.y, n3 = mm.z, n4 = mm.w, n5 = mr;

        if (j < 8) {                                    // top taps -> acc[j]
            acc[j][0] += w0*n0 + w1*n1 + w2*n2;
            acc[j][1] += w0*n1 + w1*n2 + w2*n3;
            acc[j][2] += w0*n2 + w1*n3 + w2*n4;
            acc[j][3] += w0*n3 + w1*n4 + w2*n5;
        }
        if (j >= 1 && j <= 8) {                         // mid taps -> acc[j-1]
            acc[j-1][0] += w3*n0 + w4*n1 + w5*n2;
            acc[j-1][1] += w3*n1 + w4*n2 + w5*n3;
            acc[j-1][2] += w3*n2 + w4*n3 + w5*n4;
            acc[j-1][3] += w3*n3 + w4*n4 + w5*n5;
        }
        if (j >= 2) {                                   // bottom taps -> acc[j-2]
            acc[j-2][0] += w6*n0 + w7*n1 + w8*n2;
            acc[j-2][1] += w6*n1 + w7*n2 + w8*n3;
            acc[j-2][2] += w6*n2 + w7*n3 + w8*n4;
            acc[j-2][3] += w6*n3 + w7*n4 + w8*n5;
        }
    }

    // ---- stores: 8 rows x float4, regular stores (L2 merges lines) ----
    if (act) {
        float* op = out + (size_t)plane * HW + (rq * 8) * W_ + c0;
        #pragma unroll
        for (int o = 0; o < 8; ++o) {
            v4f v;
            v.x = acc[o][0]; v.y = acc[o][1]; v.z = acc[o][2]; v.w = acc[o][3];
            *(v4f*)(op + o * W_) = v;
        }
    }
}

extern "C" void kernel_launch(void* const* d_in, const int* in_sizes, int n_in,
                              void* d_out, int out_size, void* d_ws, size_t ws_size,
                              hipStream_t stream) {
    const float* x  = (const float*)d_in[0];   // [B,C,H,W]
    const float* Wk = (const float*)d_in[1];   // [C*K*K, C]
    const float* bk = (const float*)d_in[2];   // [C*K*K]
    float* out = (float*)d_out;                // [B,C,H,W]

    float* pooled = (float*)d_ws;              // B*C = 8192 floats

    pool_kernel<<<NPLANES / 4, 256, 0, stream>>>(x, pooled);
    dconv_kernel<<<NPLANES / 2, 256, 0, stream>>>(x, pooled, Wk, bk, out);
}